// Round 7
// baseline (253.204 us; speedup 1.0000x reference)
//
#include <hip/hip_runtime.h>
#include <hip/hip_bf16.h>
#include <stdint.h>
#include <math.h>

// Problem constants (fixed by setup_inputs): B=1, S=2048, H=2048, nh=16, nkv=4, hd=128
#define SS 2048
#define HH 2048
#define NH 16
#define NKV 4
#define HD 128
#define HKV 512   // NKV*HD
#define NQKV 3072 // H + 2*HKV

typedef __bf16 bf16x8 __attribute__((ext_vector_type(8)));
typedef float f32x4 __attribute__((ext_vector_type(4)));

static_assert(sizeof(bf16x8) == 16, "bf16x8 must be 16B");

__device__ __forceinline__ void async_ld16(const void* gp, void* lp) {
  __builtin_amdgcn_global_load_lds(
      (const __attribute__((address_space(1))) unsigned int*)(uintptr_t)gp,
      (__attribute__((address_space(3))) unsigned int*)(uintptr_t)lp,
      16, 0, 0);
}

__device__ __forceinline__ unsigned short f2bu(float f) {
  __hip_bfloat16 b = __float2bfloat16(f);
  return *reinterpret_cast<unsigned short*>(&b);
}

// ---------------- prep1: X->bf16 convert + all 4 weight transpose-converts ------
__global__ __launch_bounds__(256) void k_prep1(
    const float* __restrict__ X, const float* __restrict__ Wq, const float* __restrict__ Wk,
    const float* __restrict__ Wv, const float* __restrict__ Wo,
    __hip_bfloat16* __restrict__ Xb, __hip_bfloat16* __restrict__ WqT,
    __hip_bfloat16* __restrict__ WkT, __hip_bfloat16* __restrict__ WvT,
    __hip_bfloat16* __restrict__ WoT) {
  __shared__ float tile[32][33];
  int b = blockIdx.x;
  if (b < 4096) {  // convert X
    int i = b * 256 + threadIdx.y * 32 + threadIdx.x;
    float4 v = ((const float4*)X)[i];
    ushort4 o;
    o.x = f2bu(v.x); o.y = f2bu(v.y); o.z = f2bu(v.z); o.w = f2bu(v.w);
    ((ushort4*)Xb)[i] = o;
    return;
  }
  b -= 4096;
  const float* src; __hip_bfloat16* dst; int xtiles;
  if (b < 4096)      { src = Wq; dst = WqT; xtiles = 64; }
  else if (b < 8192) { src = Wo; dst = WoT; xtiles = 64; b -= 4096; }
  else if (b < 9216) { src = Wk; dst = WkT; xtiles = 16; b -= 8192; }
  else               { src = Wv; dst = WvT; xtiles = 16; b -= 9216; }
  const int C = xtiles * 32;
  int bx = (b % xtiles) * 32;
  int by = (b / xtiles) * 32;
  int tx = threadIdx.x, ty = threadIdx.y;
#pragma unroll
  for (int i = 0; i < 4; i++)
    tile[ty + i * 8][tx] = src[(size_t)(by + ty + i * 8) * C + bx + tx];
  __syncthreads();
#pragma unroll
  for (int i = 0; i < 4; i++)
    dst[(size_t)(bx + ty + i * 8) * HH + by + tx] = __float2bfloat16(tile[tx][ty + i * 8]);
}

// ---------------- prep2v: V bf16 transpose [S][HKV] -> [HKV][S] ----------------
__global__ __launch_bounds__(256) void k_prep2v(
    const __hip_bfloat16* __restrict__ Vb, __hip_bfloat16* __restrict__ Vt) {
  __shared__ __hip_bfloat16 tile[32][33];
  int bx = blockIdx.x * 32;  // over HKV
  int by = blockIdx.y * 32;  // over S
  int tx = threadIdx.x, ty = threadIdx.y;
#pragma unroll
  for (int i = 0; i < 4; i++)
    tile[ty + i * 8][tx] = Vb[(size_t)(by + ty + i * 8) * HKV + bx + tx];
  __syncthreads();
#pragma unroll
  for (int i = 0; i < 4; i++)
    Vt[(size_t)(bx + ty + i * 8) * SS + by + tx] = tile[tx][ty + i * 8];
}

// ---------------- QKV GEMM + RoPE epilogue: 128Mx96N tile, BK=64 dbuf -----------
// Grid (3072/96=32, 2048/128=16) = 512 blocks = 2/CU (balanced). Waves 2x2 over
// (64M, 48N): 24 MFMA per 14 ds_read_b128 per 64-k step (vs 16:12 before).
// Epilogue applies RoPE to Q (pre-scaled by 1/sqrt(d)*log2e) and K on fp32
// accumulators (pair partner via shfl_xor(1)); V written straight. Q/K/V branch
// decided per 16-col j-tile (boundaries 2048/2560 are 16-aligned).
__global__ __launch_bounds__(256, 2) void k_gemm_qkv(
    const __hip_bfloat16* __restrict__ A, const __hip_bfloat16* __restrict__ B,
    __hip_bfloat16* __restrict__ Qb, __hip_bfloat16* __restrict__ Kb,
    __hip_bfloat16* __restrict__ Vb, const int* __restrict__ pos) {
  __shared__ __align__(16) __hip_bfloat16 sA0[128 * 64];
  __shared__ __align__(16) __hip_bfloat16 sA1[128 * 64];
  __shared__ __align__(16) __hip_bfloat16 sB0[96 * 64];
  __shared__ __align__(16) __hip_bfloat16 sB1[96 * 64];
  const int tid = threadIdx.x;
  const int lane = tid & 63;
  const int wave = tid >> 6;
  const int bm = blockIdx.y * 128;
  const int bn = blockIdx.x * 96;
  const int wm = (wave & 1) * 64;
  const int wn = (wave >> 1) * 48;
  const int am = lane & 15;
  const int ch = lane >> 4;

  f32x4 acc[4][3] = {};

  auto stage = [&](__hip_bfloat16* sA, __hip_bfloat16* sB, int k0) {
#pragma unroll
    for (int q = 0; q < 4; q++) {        // A: 1024 chunks (128 rows x 8)
      int c = q * 256 + tid;
      int row = c >> 3, kp = c & 7;
      int col = (kp ^ (row & 7)) * 8;
      async_ld16(A + (size_t)(bm + row) * HH + k0 + col, (char*)sA + c * 16);
    }
#pragma unroll
    for (int q = 0; q < 3; q++) {        // B: 768 chunks (96 rows x 8)
      int c = q * 256 + tid;
      int row = c >> 3, kp = c & 7;
      int col = (kp ^ (row & 7)) * 8;
      async_ld16(B + (size_t)(bn + row) * HH + k0 + col, (char*)sB + c * 16);
    }
  };
  auto compute = [&](const __hip_bfloat16* sA, const __hip_bfloat16* sB) {
#pragma unroll
    for (int kb = 0; kb < 2; kb++) {
      bf16x8 a[4], b[3];
#pragma unroll
      for (int i = 0; i < 4; i++) {
        int row = wm + i * 16 + am;
        a[i] = *(const bf16x8*)(sA + row * 64 + (((kb * 4 + ch) ^ (row & 7)) * 8));
      }
#pragma unroll
      for (int j = 0; j < 3; j++) {
        int row = wn + j * 16 + am;
        b[j] = *(const bf16x8*)(sB + row * 64 + (((kb * 4 + ch) ^ (row & 7)) * 8));
      }
#pragma unroll
      for (int i = 0; i < 4; i++)
#pragma unroll
        for (int j = 0; j < 3; j++)
          acc[i][j] = __builtin_amdgcn_mfma_f32_16x16x32_bf16(a[i], b[j], acc[i][j], 0, 0, 0);
    }
  };

  stage(sA0, sB0, 0);
  int k0 = 0;
  while (true) {
    __syncthreads();
    if (k0 + 64 < HH) stage(sA1, sB1, k0 + 64);
    compute(sA0, sB0);
    k0 += 64; if (k0 >= HH) break;
    __syncthreads();
    if (k0 + 64 < HH) stage(sA0, sB0, k0 + 64);
    compute(sA1, sB1);
    k0 += 64; if (k0 >= HH) break;
  }

  const float SCLQ = 0.08838834764831845f * 1.4426950408889634f; // 1/sqrt(128)*log2e
  const float L2T_D64 = 0.20762050593046837f;                    // log2(10000)/64
  float posr[4][4];
#pragma unroll
  for (int i = 0; i < 4; i++)
#pragma unroll
    for (int r = 0; r < 4; r++)
      posr[i][r] = (float)pos[bm + wm + i * 16 + ch * 4 + r];
  const float sgn = (am & 1) ? 1.0f : -1.0f;
#pragma unroll
  for (int j = 0; j < 3; j++) {
    int colb = bn + wn + j * 16;       // 16-aligned; uniform Q/K/V per j-tile
    int col = colb + am;
    if (colb >= HH + HKV) {            // V
#pragma unroll
      for (int i = 0; i < 4; i++)
#pragma unroll
        for (int r = 0; r < 4; r++) {
          int row = bm + wm + i * 16 + ch * 4 + r;
          Vb[(size_t)row * HKV + (col - HH - HKV)] = __float2bfloat16(acc[i][j][r]);
        }
    } else {
      const bool isQ = (colb < HH);
      int lc = isQ ? col : (col - HH);
      float freq = exp2f(-L2T_D64 * (float)((lc >> 1) & 63));
#pragma unroll
      for (int i = 0; i < 4; i++)
#pragma unroll
        for (int r = 0; r < 4; r++) {
          float v = acc[i][j][r];
          float px = __shfl_xor(v, 1, 64);
          float ang = posr[i][r] * freq;
          float sn, cs;
          sincosf(ang, &sn, &cs);
          float o = v * cs + sgn * px * sn;
          int row = bm + wm + i * 16 + ch * 4 + r;
          if (isQ) Qb[(size_t)row * HH + col] = __float2bfloat16(o * SCLQ);
          else     Kb[(size_t)row * HKV + lc] = __float2bfloat16(o);
        }
    }
  }
}

// ---------------- out-proj GEMM: 128x128 tile, BK=64 dbuf, split-K=2 ------------
// Grid (16,16,2) = 512 blocks = 2/CU; wave tile 64x64 (32 MFMA : 16 reads).
// Each z-block does K=1024 (16 steps); partials merged via fp32 HW atomics into
// C (zeroed by hipMemsetAsync before launch).
__global__ __launch_bounds__(256, 2) void k_gemm_out(
    const __hip_bfloat16* __restrict__ A, const __hip_bfloat16* __restrict__ B,
    float* __restrict__ C) {
  __shared__ __align__(16) __hip_bfloat16 sA0[128 * 64];
  __shared__ __align__(16) __hip_bfloat16 sA1[128 * 64];
  __shared__ __align__(16) __hip_bfloat16 sB0[128 * 64];
  __shared__ __align__(16) __hip_bfloat16 sB1[128 * 64];
  const int tid = threadIdx.x;
  const int lane = tid & 63;
  const int wave = tid >> 6;
  const int bm = blockIdx.y * 128;
  const int bn = blockIdx.x * 128;
  const int kbase = blockIdx.z * 1024;
  const int wm = (wave & 1) * 64;
  const int wn = (wave >> 1) * 64;
  const int am = lane & 15;
  const int ch = lane >> 4;

  f32x4 acc[4][4] = {};

  auto stage = [&](__hip_bfloat16* sA, __hip_bfloat16* sB, int k0) {
#pragma unroll
    for (int q = 0; q < 4; q++) {
      int c = q * 256 + tid;
      int row = c >> 3, kp = c & 7;
      int col = (kp ^ (row & 7)) * 8;
      async_ld16(A + (size_t)(bm + row) * HH + k0 + col, (char*)sA + c * 16);
      async_ld16(B + (size_t)(bn + row) * HH + k0 + col, (char*)sB + c * 16);
    }
  };
  auto compute = [&](const __hip_bfloat16* sA, const __hip_bfloat16* sB) {
#pragma unroll
    for (int kb = 0; kb < 2; kb++) {
      bf16x8 a[4], b[4];
#pragma unroll
      for (int i = 0; i < 4; i++) {
        int row = wm + i * 16 + am;
        a[i] = *(const bf16x8*)(sA + row * 64 + (((kb * 4 + ch) ^ (row & 7)) * 8));
      }
#pragma unroll
      for (int j = 0; j < 4; j++) {
        int row = wn + j * 16 + am;
        b[j] = *(const bf16x8*)(sB + row * 64 + (((kb * 4 + ch) ^ (row & 7)) * 8));
      }
#pragma unroll
      for (int i = 0; i < 4; i++)
#pragma unroll
        for (int j = 0; j < 4; j++)
          acc[i][j] = __builtin_amdgcn_mfma_f32_16x16x32_bf16(a[i], b[j], acc[i][j], 0, 0, 0);
    }
  };

  stage(sA0, sB0, kbase);
  int k0 = kbase;
  const int kend = kbase + 1024;
  while (true) {
    __syncthreads();
    if (k0 + 64 < kend) stage(sA1, sB1, k0 + 64);
    compute(sA0, sB0);
    k0 += 64; if (k0 >= kend) break;
    __syncthreads();
    if (k0 + 64 < kend) stage(sA0, sB0, k0 + 64);
    compute(sA1, sB1);
    k0 += 64; if (k0 >= kend) break;
  }

#pragma unroll
  for (int i = 0; i < 4; i++)
#pragma unroll
    for (int j = 0; j < 4; j++)
#pragma unroll
      for (int r = 0; r < 4; r++) {
        int row = bm + wm + i * 16 + ch * 4 + r;
        int col = bn + wn + j * 16 + am;
        unsafeAtomicAdd(C + (size_t)row * HH + col, acc[i][j][r]);
      }
}

// ---------------- flash attention (round-4/6 config, verified 67.7us) ------------
__global__ __launch_bounds__(256, 2) void k_attn(
    const __hip_bfloat16* __restrict__ Qb,   // [S][H], pre-scaled by 1/sqrt(d)*log2e
    const __hip_bfloat16* __restrict__ Kb,   // [S][HKV]
    const __hip_bfloat16* __restrict__ Vt,   // [HKV][S]
    const int* __restrict__ amv, const int* __restrict__ seg,
    __hip_bfloat16* __restrict__ O) {        // [S][H]
  __shared__ __align__(16) __hip_bfloat16 sK[2][64 * 128];  // 2x16KB, [key][d]
  __shared__ __align__(16) __hip_bfloat16 sV[2][128 * 64];  // 2x16KB, [d][key]
  __shared__ __align__(16) __hip_bfloat16 sPall[4][16 * 64]; // 8KB, per-wave
  __shared__ int sInfo[2][64];

  const int id = blockIdx.x;
  const int a0 = id & 255;
  const int h = a0 >> 4;
  const int qh = a0 & 15;
  const int qt = (id >> 8) ? (31 - qh) : qh;
  const int kvh = h >> 2;
  const int tid = threadIdx.x, lane = tid & 63, w = tid >> 6;
  const int am = lane & 15, ch = lane >> 4;
  const int qrow0 = qt * 64 + w * 16;
  char* sP = (char*)&sPall[w][0];

  bf16x8 qf[4];
#pragma unroll
  for (int ks = 0; ks < 4; ks++)
    qf[ks] = *(const bf16x8*)(Qb + (size_t)(qrow0 + am) * HH + h * HD + ks * 32 + ch * 8);

  int segq[4];
#pragma unroll
  for (int r = 0; r < 4; r++) segq[r] = seg[qrow0 + ch * 4 + r];

  f32x4 o_acc[8] = {};
  float l_s[4] = {0.f, 0.f, 0.f, 0.f};

  auto stage = [&](int kt, int p) {
#pragma unroll
    for (int q = 0; q < 4; q++) {        // K tile: 1024 chunks, [key][16 chunks]
      int c = q * 256 + tid;
      int row = c >> 4, kp = c & 15;
      int col = (kp ^ (row & 15)) * 8;
      async_ld16(Kb + (size_t)(kt * 64 + row) * HKV + kvh * 128 + col, (char*)sK[p] + c * 16);
    }
#pragma unroll
    for (int q = 0; q < 4; q++) {        // V tile: 1024 chunks, [d][8 chunks]
      int c = q * 256 + tid;
      int row = c >> 3, kp = c & 7;
      int col = (kp ^ (row & 7)) * 8;
      async_ld16(Vt + (size_t)(kvh * 128 + row) * SS + kt * 64 + col, (char*)sV[p] + c * 16);
    }
    if (tid < 64) {
      int kidx = kt * 64 + tid;
      sInfo[p][tid] = (amv[kidx] > 0) ? seg[kidx] : 0x7fffffff;
    }
  };

  stage(0, 0);
  for (int kt = 0; kt <= qt; kt++) {
    const int p = kt & 1;
    __syncthreads();
    if (kt < qt) stage(kt + 1, p ^ 1);

    // S = Q K^T  (M=16 q, N=64 keys, K=128)
    f32x4 sacc[4] = {};
#pragma unroll
    for (int ks = 0; ks < 4; ks++)
#pragma unroll
      for (int jt = 0; jt < 4; jt++) {
        bf16x8 kf = *(const bf16x8*)(sK[p] + (jt * 16 + am) * 128 + (((ks * 4 + ch) ^ am) * 8));
        sacc[jt] = __builtin_amdgcn_mfma_f32_16x16x32_bf16(qf[ks], kf, sacc[jt], 0, 0, 0);
      }

#pragma unroll
    for (int jt = 0; jt < 4; jt++) {
      int kloc = jt * 16 + am;
      int kinfo = sInfo[p][kloc];
#pragma unroll
      for (int r = 0; r < 4; r++) {
        int qrow = qrow0 + ch * 4 + r;
        bool ok = (kinfo == segq[r]) && (kt * 64 + kloc <= qrow);
        float pv = ok ? exp2f(sacc[jt][r] - 8.0f) : 0.0f;
        l_s[r] += pv;
        int row = ch * 4 + r;
        int chunk = (jt * 2 + (am >> 3)) ^ (row & 7);
        *(__hip_bfloat16*)(sP + row * 128 + chunk * 16 + (am & 7) * 2) =
            __float2bfloat16(pv);
      }
    }

    // O += P V  (M=16 q, N=128 d, K=64 keys)
#pragma unroll
    for (int ks = 0; ks < 2; ks++) {
      bf16x8 pf = *(const bf16x8*)(sP + am * 128 + (((ks * 4 + ch) ^ (am & 7)) * 16));
#pragma unroll
      for (int jt = 0; jt < 8; jt++) {
        int vrow = jt * 16 + am;
        bf16x8 vf = *(const bf16x8*)(sV[p] + vrow * 64 + (((ks * 4 + ch) ^ (vrow & 7)) * 8));
        o_acc[jt] = __builtin_amdgcn_mfma_f32_16x16x32_bf16(pf, vf, o_acc[jt], 0, 0, 0);
      }
    }
  }

#pragma unroll
  for (int off = 1; off < 16; off <<= 1)
#pragma unroll
    for (int r = 0; r < 4; r++) l_s[r] += __shfl_xor(l_s[r], off, 64);
  float inv[4];
#pragma unroll
  for (int r = 0; r < 4; r++) inv[r] = 1.0f / l_s[r];
#pragma unroll
  for (int jt = 0; jt < 8; jt++)
#pragma unroll
    for (int r = 0; r < 4; r++) {
      int row = qrow0 + ch * 4 + r;
      O[(size_t)row * HH + h * HD + jt * 16 + am] = __float2bfloat16(o_acc[jt][r] * inv[r]);
    }
}

extern "C" void kernel_launch(void* const* d_in, const int* in_sizes, int n_in,
                              void* d_out, int out_size, void* d_ws, size_t ws_size,
                              hipStream_t stream) {
  const float* X  = (const float*)d_in[0];
  const int* amv  = (const int*)d_in[1];
  const int* seg  = (const int*)d_in[2];
  const int* pos  = (const int*)d_in[3];
  const float* Wq = (const float*)d_in[4];
  const float* Wk = (const float*)d_in[5];
  const float* Wv = (const float*)d_in[6];
  const float* Wo = (const float*)d_in[7];
  float* out = (float*)d_out;

  // workspace carve-up (~50 MB); WqT/WkT/WvT contiguous for the fused QKV GEMM.
  char* ws = (char*)d_ws;
  size_t off = 0;
  auto alloc = [&](size_t bytes) { void* p = ws + off; off += (bytes + 255) & ~(size_t)255; return p; };
  __hip_bfloat16* Xb   = (__hip_bfloat16*)alloc((size_t)SS * HH * 2);
  __hip_bfloat16* WqT  = (__hip_bfloat16*)alloc((size_t)HH * HH * 2);
  __hip_bfloat16* WkT  = (__hip_bfloat16*)alloc((size_t)HKV * HH * 2);
  __hip_bfloat16* WvT  = (__hip_bfloat16*)alloc((size_t)HKV * HH * 2);
  __hip_bfloat16* WoT  = (__hip_bfloat16*)alloc((size_t)HH * HH * 2);
  __hip_bfloat16* Qb   = (__hip_bfloat16*)alloc((size_t)SS * HH * 2);
  __hip_bfloat16* Kb   = (__hip_bfloat16*)alloc((size_t)SS * HKV * 2);
  __hip_bfloat16* Vb   = (__hip_bfloat16*)alloc((size_t)SS * HKV * 2);
  __hip_bfloat16* Vt   = (__hip_bfloat16*)alloc((size_t)HKV * SS * 2);
  __hip_bfloat16* Ab   = (__hip_bfloat16*)alloc((size_t)SS * HH * 2);
  (void)WkT; (void)WvT;

  // 0) zero d_out for the atomic split-K accumulate (harness re-poisons it)
  hipMemsetAsync(out, 0, (size_t)SS * HH * 4, stream);
  // 1) convert X + transpose-convert all weights (one launch)
  k_prep1<<<dim3(14336), dim3(32, 8), 0, stream>>>(X, Wq, Wk, Wv, Wo, Xb, WqT, WkT, WvT, WoT);
  // 2) fused QKV projection with RoPE epilogue -> Qb (scaled), Kb, Vb
  k_gemm_qkv<<<dim3(NQKV / 96, SS / 128), 256, 0, stream>>>(Xb, WqT, Qb, Kb, Vb, pos);
  // 3) V transpose to [HKV][S]
  k_prep2v<<<dim3(HKV / 32, SS / 32), dim3(32, 8), 0, stream>>>(Vb, Vt);
  // 4) attention (verified config: 512 balanced blocks, 64-key dbuf tiles)
  k_attn<<<dim3(512), 256, 0, stream>>>(Qb, Kb, Vt, amv, seg, Ab);
  // 5) output projection: 128x128 BK=64 dbuf, split-K=2, atomic merge
  k_gemm_out<<<dim3(HH / 128, SS / 128, 2), 256, 0, stream>>>(Ab, WoT, out);
}

// Round 8
// 239.953 us; speedup vs baseline: 1.0552x; 1.0552x over previous
//
#include <hip/hip_runtime.h>
#include <hip/hip_bf16.h>
#include <stdint.h>
#include <math.h>

// Problem constants (fixed by setup_inputs): B=1, S=2048, H=2048, nh=16, nkv=4, hd=128
#define SS 2048
#define HH 2048
#define NH 16
#define NKV 4
#define HD 128
#define HKV 512   // NKV*HD
#define NQKV 3072 // H + 2*HKV

typedef __bf16 bf16x8 __attribute__((ext_vector_type(8)));
typedef float f32x4 __attribute__((ext_vector_type(4)));

static_assert(sizeof(bf16x8) == 16, "bf16x8 must be 16B");

__device__ __forceinline__ void async_ld16(const void* gp, void* lp) {
  __builtin_amdgcn_global_load_lds(
      (const __attribute__((address_space(1))) unsigned int*)(uintptr_t)gp,
      (__attribute__((address_space(3))) unsigned int*)(uintptr_t)lp,
      16, 0, 0);
}

__device__ __forceinline__ unsigned short f2bu(float f) {
  __hip_bfloat16 b = __float2bfloat16(f);
  return *reinterpret_cast<unsigned short*>(&b);
}

// ---------------- prep1: X->bf16 convert + all 4 weight transpose-converts ------
__global__ __launch_bounds__(256) void k_prep1(
    const float* __restrict__ X, const float* __restrict__ Wq, const float* __restrict__ Wk,
    const float* __restrict__ Wv, const float* __restrict__ Wo,
    __hip_bfloat16* __restrict__ Xb, __hip_bfloat16* __restrict__ WqT,
    __hip_bfloat16* __restrict__ WkT, __hip_bfloat16* __restrict__ WvT,
    __hip_bfloat16* __restrict__ WoT) {
  __shared__ float tile[32][33];
  int b = blockIdx.x;
  if (b < 4096) {  // convert X
    int i = b * 256 + threadIdx.y * 32 + threadIdx.x;
    float4 v = ((const float4*)X)[i];
    ushort4 o;
    o.x = f2bu(v.x); o.y = f2bu(v.y); o.z = f2bu(v.z); o.w = f2bu(v.w);
    ((ushort4*)Xb)[i] = o;
    return;
  }
  b -= 4096;
  const float* src; __hip_bfloat16* dst; int xtiles;
  if (b < 4096)      { src = Wq; dst = WqT; xtiles = 64; }
  else if (b < 8192) { src = Wo; dst = WoT; xtiles = 64; b -= 4096; }
  else if (b < 9216) { src = Wk; dst = WkT; xtiles = 16; b -= 8192; }
  else               { src = Wv; dst = WvT; xtiles = 16; b -= 9216; }
  const int C = xtiles * 32;
  int bx = (b % xtiles) * 32;
  int by = (b / xtiles) * 32;
  int tx = threadIdx.x, ty = threadIdx.y;
#pragma unroll
  for (int i = 0; i < 4; i++)
    tile[ty + i * 8][tx] = src[(size_t)(by + ty + i * 8) * C + bx + tx];
  __syncthreads();
#pragma unroll
  for (int i = 0; i < 4; i++)
    dst[(size_t)(bx + ty + i * 8) * HH + by + tx] = __float2bfloat16(tile[tx][ty + i * 8]);
}

// ---------------- QKV GEMM + RoPE/V-transpose epilogue ----------------
// Round-6 config (verified best): 64Mx128N tile, BK=64 dbuf, 48KB LDS,
// grid (24,32)=768 blocks = 3/CU. Waves 2x2 over (32M, 64N).
// Epilogue: Q cols get RoPE * 1/sqrt(d)*log2e; K cols get RoPE; V cols are
// written TRANSPOSED into Vt[HKV][S] (packed 8B stores) — no separate
// transpose kernel. Q/K/V region is block-uniform (boundaries 128-aligned).
__global__ __launch_bounds__(256, 3) void k_gemm_qkv(
    const __hip_bfloat16* __restrict__ A, const __hip_bfloat16* __restrict__ B,
    __hip_bfloat16* __restrict__ Qb, __hip_bfloat16* __restrict__ Kb,
    __hip_bfloat16* __restrict__ Vt, const int* __restrict__ pos) {
  __shared__ __align__(16) __hip_bfloat16 sA0[64 * 64];
  __shared__ __align__(16) __hip_bfloat16 sB0[128 * 64];
  __shared__ __align__(16) __hip_bfloat16 sA1[64 * 64];
  __shared__ __align__(16) __hip_bfloat16 sB1[128 * 64];
  const int tid = threadIdx.x;
  const int lane = tid & 63;
  const int wave = tid >> 6;
  const int bm = blockIdx.y * 64;
  const int bn = blockIdx.x * 128;
  const int wm = (wave & 1) * 32;
  const int wn = (wave >> 1) * 64;
  const int am = lane & 15;
  const int ch = lane >> 4;

  f32x4 acc[2][4] = {};

  auto stage = [&](__hip_bfloat16* sA, __hip_bfloat16* sB, int k0) {
#pragma unroll
    for (int q = 0; q < 2; q++) {        // A: 512 chunks (64 rows x 8)
      int c = q * 256 + tid;
      int row = c >> 3, kp = c & 7;
      int col = (kp ^ (row & 7)) * 8;
      async_ld16(A + (size_t)(bm + row) * HH + k0 + col, (char*)sA + c * 16);
    }
#pragma unroll
    for (int q = 0; q < 4; q++) {        // B: 1024 chunks (128 rows x 8)
      int c = q * 256 + tid;
      int row = c >> 3, kp = c & 7;
      int col = (kp ^ (row & 7)) * 8;
      async_ld16(B + (size_t)(bn + row) * HH + k0 + col, (char*)sB + c * 16);
    }
  };
  auto compute = [&](const __hip_bfloat16* sA, const __hip_bfloat16* sB) {
#pragma unroll
    for (int kb = 0; kb < 2; kb++) {
      bf16x8 a[2], b[4];
#pragma unroll
      for (int i = 0; i < 2; i++) {
        int row = wm + i * 16 + am;
        a[i] = *(const bf16x8*)(sA + row * 64 + (((kb * 4 + ch) ^ (row & 7)) * 8));
      }
#pragma unroll
      for (int j = 0; j < 4; j++) {
        int row = wn + j * 16 + am;
        b[j] = *(const bf16x8*)(sB + row * 64 + (((kb * 4 + ch) ^ (row & 7)) * 8));
      }
#pragma unroll
      for (int i = 0; i < 2; i++)
#pragma unroll
        for (int j = 0; j < 4; j++)
          acc[i][j] = __builtin_amdgcn_mfma_f32_16x16x32_bf16(a[i], b[j], acc[i][j], 0, 0, 0);
    }
  };

  stage(sA0, sB0, 0);
  int k0 = 0;
  while (true) {
    __syncthreads();
    if (k0 + 64 < HH) stage(sA1, sB1, k0 + 64);
    compute(sA0, sB0);
    k0 += 64; if (k0 >= HH) break;
    __syncthreads();
    if (k0 + 64 < HH) stage(sA0, sB0, k0 + 64);
    compute(sA1, sB1);
    k0 += 64; if (k0 >= HH) break;
  }

  const bool isV = (bn >= HH + HKV);     // block-uniform (2560 is 128-aligned)
  if (isV) {
    // write V transposed: Vt[kvdim][seqpos], 4 rows packed per 8B store
#pragma unroll
    for (int j = 0; j < 4; j++) {
      int lc = bn + wn + j * 16 + am - (HH + HKV);
#pragma unroll
      for (int i = 0; i < 2; i++) {
        int row = bm + wm + i * 16 + ch * 4;
        ushort4 o;
        o.x = f2bu(acc[i][j][0]); o.y = f2bu(acc[i][j][1]);
        o.z = f2bu(acc[i][j][2]); o.w = f2bu(acc[i][j][3]);
        *(ushort4*)(Vt + (size_t)lc * SS + row) = o;
      }
    }
  } else {
    const float SCLQ = 0.08838834764831845f * 1.4426950408889634f; // 1/sqrt(128)*log2e
    const float L2T_D64 = 0.20762050593046837f;                    // log2(10000)/64
    const bool isQ = (bn < HH);          // block-uniform (2048 is 128-aligned)
    float posr[2][4];
#pragma unroll
    for (int i = 0; i < 2; i++)
#pragma unroll
      for (int r = 0; r < 4; r++)
        posr[i][r] = (float)pos[bm + wm + i * 16 + ch * 4 + r];
    const float sgn = (am & 1) ? 1.0f : -1.0f;
#pragma unroll
    for (int j = 0; j < 4; j++) {
      int col = bn + wn + j * 16 + am;
      int lc = isQ ? col : (col - HH);
      float freq = exp2f(-L2T_D64 * (float)((lc >> 1) & 63));
#pragma unroll
      for (int i = 0; i < 2; i++)
#pragma unroll
        for (int r = 0; r < 4; r++) {
          float v = acc[i][j][r];
          float px = __shfl_xor(v, 1, 64);
          float ang = posr[i][r] * freq;
          float sn, cs;
          sincosf(ang, &sn, &cs);
          float o = v * cs + sgn * px * sn;
          int row = bm + wm + i * 16 + ch * 4 + r;
          if (isQ) Qb[(size_t)row * HH + col] = __float2bfloat16(o * SCLQ);
          else     Kb[(size_t)row * HKV + lc] = __float2bfloat16(o);
        }
    }
  }
}

// ---------------- out-proj GEMM: 64x64 tile, BK=64 dbuf, 4 blocks/CU ------------
// Grid (32,32) = 1024 blocks; LDS 32KB -> 4 blocks/CU = 16 waves/CU.
// Waves 2x2 over (32M, 32N): 8 MFMA : 8 ds_read per 64-k step — worse ratio
// than 64x128 but double the co-residency (occupancy rule from rounds 6/7).
__global__ __launch_bounds__(256, 4) void k_gemm_out(
    const __hip_bfloat16* __restrict__ A, const __hip_bfloat16* __restrict__ B,
    float* __restrict__ C) {
  __shared__ __align__(16) __hip_bfloat16 sA0[64 * 64];
  __shared__ __align__(16) __hip_bfloat16 sB0[64 * 64];
  __shared__ __align__(16) __hip_bfloat16 sA1[64 * 64];
  __shared__ __align__(16) __hip_bfloat16 sB1[64 * 64];
  const int tid = threadIdx.x;
  const int lane = tid & 63;
  const int wave = tid >> 6;
  const int bm = blockIdx.y * 64;
  const int bn = blockIdx.x * 64;
  const int wm = (wave & 1) * 32;
  const int wn = (wave >> 1) * 32;
  const int am = lane & 15;
  const int ch = lane >> 4;

  f32x4 acc[2][2] = {};

  auto stage = [&](__hip_bfloat16* sA, __hip_bfloat16* sB, int k0) {
#pragma unroll
    for (int q = 0; q < 2; q++) {        // A: 512 chunks (64 rows x 8)
      int c = q * 256 + tid;
      int row = c >> 3, kp = c & 7;
      int col = (kp ^ (row & 7)) * 8;
      async_ld16(A + (size_t)(bm + row) * HH + k0 + col, (char*)sA + c * 16);
    }
#pragma unroll
    for (int q = 0; q < 2; q++) {        // B: 512 chunks (64 rows x 8)
      int c = q * 256 + tid;
      int row = c >> 3, kp = c & 7;
      int col = (kp ^ (row & 7)) * 8;
      async_ld16(B + (size_t)(bn + row) * HH + k0 + col, (char*)sB + c * 16);
    }
  };
  auto compute = [&](const __hip_bfloat16* sA, const __hip_bfloat16* sB) {
#pragma unroll
    for (int kb = 0; kb < 2; kb++) {
      bf16x8 a[2], b[2];
#pragma unroll
      for (int i = 0; i < 2; i++) {
        int row = wm + i * 16 + am;
        a[i] = *(const bf16x8*)(sA + row * 64 + (((kb * 4 + ch) ^ (row & 7)) * 8));
      }
#pragma unroll
      for (int j = 0; j < 2; j++) {
        int row = wn + j * 16 + am;
        b[j] = *(const bf16x8*)(sB + row * 64 + (((kb * 4 + ch) ^ (row & 7)) * 8));
      }
#pragma unroll
      for (int i = 0; i < 2; i++)
#pragma unroll
        for (int j = 0; j < 2; j++)
          acc[i][j] = __builtin_amdgcn_mfma_f32_16x16x32_bf16(a[i], b[j], acc[i][j], 0, 0, 0);
    }
  };

  stage(sA0, sB0, 0);
  int k0 = 0;
  while (true) {
    __syncthreads();
    if (k0 + 64 < HH) stage(sA1, sB1, k0 + 64);
    compute(sA0, sB0);
    k0 += 64; if (k0 >= HH) break;
    __syncthreads();
    if (k0 + 64 < HH) stage(sA0, sB0, k0 + 64);
    compute(sA1, sB1);
    k0 += 64; if (k0 >= HH) break;
  }

#pragma unroll
  for (int i = 0; i < 2; i++)
#pragma unroll
    for (int j = 0; j < 2; j++)
#pragma unroll
      for (int r = 0; r < 4; r++) {
        int row = bm + wm + i * 16 + ch * 4 + r;
        int col = bn + wn + j * 16 + am;
        C[(size_t)row * HH + col] = acc[i][j][r];
      }
}

// ---------------- flash attention (verified config, ~65us) ----------------
__global__ __launch_bounds__(256, 2) void k_attn(
    const __hip_bfloat16* __restrict__ Qb,   // [S][H], pre-scaled by 1/sqrt(d)*log2e
    const __hip_bfloat16* __restrict__ Kb,   // [S][HKV]
    const __hip_bfloat16* __restrict__ Vt,   // [HKV][S]
    const int* __restrict__ amv, const int* __restrict__ seg,
    __hip_bfloat16* __restrict__ O) {        // [S][H]
  __shared__ __align__(16) __hip_bfloat16 sK[2][64 * 128];  // 2x16KB, [key][d]
  __shared__ __align__(16) __hip_bfloat16 sV[2][128 * 64];  // 2x16KB, [d][key]
  __shared__ __align__(16) __hip_bfloat16 sPall[4][16 * 64]; // 8KB, per-wave
  __shared__ int sInfo[2][64];

  const int id = blockIdx.x;
  const int a0 = id & 255;
  const int h = a0 >> 4;
  const int qh = a0 & 15;
  const int qt = (id >> 8) ? (31 - qh) : qh;
  const int kvh = h >> 2;
  const int tid = threadIdx.x, lane = tid & 63, w = tid >> 6;
  const int am = lane & 15, ch = lane >> 4;
  const int qrow0 = qt * 64 + w * 16;
  char* sP = (char*)&sPall[w][0];

  bf16x8 qf[4];
#pragma unroll
  for (int ks = 0; ks < 4; ks++)
    qf[ks] = *(const bf16x8*)(Qb + (size_t)(qrow0 + am) * HH + h * HD + ks * 32 + ch * 8);

  int segq[4];
#pragma unroll
  for (int r = 0; r < 4; r++) segq[r] = seg[qrow0 + ch * 4 + r];

  f32x4 o_acc[8] = {};
  float l_s[4] = {0.f, 0.f, 0.f, 0.f};

  auto stage = [&](int kt, int p) {
#pragma unroll
    for (int q = 0; q < 4; q++) {        // K tile: 1024 chunks, [key][16 chunks]
      int c = q * 256 + tid;
      int row = c >> 4, kp = c & 15;
      int col = (kp ^ (row & 15)) * 8;
      async_ld16(Kb + (size_t)(kt * 64 + row) * HKV + kvh * 128 + col, (char*)sK[p] + c * 16);
    }
#pragma unroll
    for (int q = 0; q < 4; q++) {        // V tile: 1024 chunks, [d][8 chunks]
      int c = q * 256 + tid;
      int row = c >> 3, kp = c & 7;
      int col = (kp ^ (row & 7)) * 8;
      async_ld16(Vt + (size_t)(kvh * 128 + row) * SS + kt * 64 + col, (char*)sV[p] + c * 16);
    }
    if (tid < 64) {
      int kidx = kt * 64 + tid;
      sInfo[p][tid] = (amv[kidx] > 0) ? seg[kidx] : 0x7fffffff;
    }
  };

  stage(0, 0);
  for (int kt = 0; kt <= qt; kt++) {
    const int p = kt & 1;
    __syncthreads();
    if (kt < qt) stage(kt + 1, p ^ 1);

    // S = Q K^T  (M=16 q, N=64 keys, K=128)
    f32x4 sacc[4] = {};
#pragma unroll
    for (int ks = 0; ks < 4; ks++)
#pragma unroll
      for (int jt = 0; jt < 4; jt++) {
        bf16x8 kf = *(const bf16x8*)(sK[p] + (jt * 16 + am) * 128 + (((ks * 4 + ch) ^ am) * 8));
        sacc[jt] = __builtin_amdgcn_mfma_f32_16x16x32_bf16(qf[ks], kf, sacc[jt], 0, 0, 0);
      }

#pragma unroll
    for (int jt = 0; jt < 4; jt++) {
      int kloc = jt * 16 + am;
      int kinfo = sInfo[p][kloc];
#pragma unroll
      for (int r = 0; r < 4; r++) {
        int qrow = qrow0 + ch * 4 + r;
        bool ok = (kinfo == segq[r]) && (kt * 64 + kloc <= qrow);
        float pv = ok ? exp2f(sacc[jt][r] - 8.0f) : 0.0f;
        l_s[r] += pv;
        int row = ch * 4 + r;
        int chunk = (jt * 2 + (am >> 3)) ^ (row & 7);
        *(__hip_bfloat16*)(sP + row * 128 + chunk * 16 + (am & 7) * 2) =
            __float2bfloat16(pv);
      }
    }

    // O += P V  (M=16 q, N=128 d, K=64 keys)
#pragma unroll
    for (int ks = 0; ks < 2; ks++) {
      bf16x8 pf = *(const bf16x8*)(sP + am * 128 + (((ks * 4 + ch) ^ (am & 7)) * 16));
#pragma unroll
      for (int jt = 0; jt < 8; jt++) {
        int vrow = jt * 16 + am;
        bf16x8 vf = *(const bf16x8*)(sV[p] + vrow * 64 + (((ks * 4 + ch) ^ (vrow & 7)) * 8));
        o_acc[jt] = __builtin_amdgcn_mfma_f32_16x16x32_bf16(pf, vf, o_acc[jt], 0, 0, 0);
      }
    }
  }

#pragma unroll
  for (int off = 1; off < 16; off <<= 1)
#pragma unroll
    for (int r = 0; r < 4; r++) l_s[r] += __shfl_xor(l_s[r], off, 64);
  float inv[4];
#pragma unroll
  for (int r = 0; r < 4; r++) inv[r] = 1.0f / l_s[r];
#pragma unroll
  for (int jt = 0; jt < 8; jt++)
#pragma unroll
    for (int r = 0; r < 4; r++) {
      int row = qrow0 + ch * 4 + r;
      O[(size_t)row * HH + h * HD + jt * 16 + am] = __float2bfloat16(o_acc[jt][r] * inv[r]);
    }
}

extern "C" void kernel_launch(void* const* d_in, const int* in_sizes, int n_in,
                              void* d_out, int out_size, void* d_ws, size_t ws_size,
                              hipStream_t stream) {
  const float* X  = (const float*)d_in[0];
  const int* amv  = (const int*)d_in[1];
  const int* seg  = (const int*)d_in[2];
  const int* pos  = (const int*)d_in[3];
  const float* Wq = (const float*)d_in[4];
  const float* Wk = (const float*)d_in[5];
  const float* Wv = (const float*)d_in[6];
  const float* Wo = (const float*)d_in[7];
  float* out = (float*)d_out;

  // workspace carve-up (~46 MB); WqT/WkT/WvT contiguous for the fused QKV GEMM.
  char* ws = (char*)d_ws;
  size_t off = 0;
  auto alloc = [&](size_t bytes) { void* p = ws + off; off += (bytes + 255) & ~(size_t)255; return p; };
  __hip_bfloat16* Xb   = (__hip_bfloat16*)alloc((size_t)SS * HH * 2);
  __hip_bfloat16* WqT  = (__hip_bfloat16*)alloc((size_t)HH * HH * 2);
  __hip_bfloat16* WkT  = (__hip_bfloat16*)alloc((size_t)HKV * HH * 2);
  __hip_bfloat16* WvT  = (__hip_bfloat16*)alloc((size_t)HKV * HH * 2);
  __hip_bfloat16* WoT  = (__hip_bfloat16*)alloc((size_t)HH * HH * 2);
  __hip_bfloat16* Qb   = (__hip_bfloat16*)alloc((size_t)SS * HH * 2);
  __hip_bfloat16* Kb   = (__hip_bfloat16*)alloc((size_t)SS * HKV * 2);
  __hip_bfloat16* Vt   = (__hip_bfloat16*)alloc((size_t)HKV * SS * 2);
  __hip_bfloat16* Ab   = (__hip_bfloat16*)alloc((size_t)SS * HH * 2);
  (void)WkT; (void)WvT;

  // 1) convert X + transpose-convert all weights (one launch)
  k_prep1<<<dim3(14336), dim3(32, 8), 0, stream>>>(X, Wq, Wk, Wv, Wo, Xb, WqT, WkT, WvT, WoT);
  // 2) fused QKV projection: RoPE'd Qb (scaled) / Kb, V written transposed to Vt
  k_gemm_qkv<<<dim3(NQKV / 128, SS / 64), 256, 0, stream>>>(Xb, WqT, Qb, Kb, Vt, pos);
  // 3) attention (verified config: 512 balanced blocks, 64-key dbuf tiles)
  k_attn<<<dim3(512), 256, 0, stream>>>(Qb, Kb, Vt, amv, seg, Ab);
  // 4) output projection: 64x64 BK=64 dbuf, 1024 blocks = 4/CU
  k_gemm_out<<<dim3(HH / 64, SS / 64), 256, 0, stream>>>(Ab, WoT, out);
}

// Round 9
// 227.993 us; speedup vs baseline: 1.1106x; 1.0525x over previous
//
#include <hip/hip_runtime.h>
#include <hip/hip_bf16.h>
#include <stdint.h>
#include <math.h>

// Problem constants (fixed by setup_inputs): B=1, S=2048, H=2048, nh=16, nkv=4, hd=128
#define SS 2048
#define HH 2048
#define NH 16
#define NKV 4
#define HD 128
#define HKV 512   // NKV*HD
#define NQKV 3072 // H + 2*HKV

typedef __bf16 bf16x8 __attribute__((ext_vector_type(8)));
typedef float f32x4 __attribute__((ext_vector_type(4)));

static_assert(sizeof(bf16x8) == 16, "bf16x8 must be 16B");

__device__ __forceinline__ void async_ld16(const void* gp, void* lp) {
  __builtin_amdgcn_global_load_lds(
      (const __attribute__((address_space(1))) unsigned int*)(uintptr_t)gp,
      (__attribute__((address_space(3))) unsigned int*)(uintptr_t)lp,
      16, 0, 0);
}

__device__ __forceinline__ unsigned short f2bu(float f) {
  __hip_bfloat16 b = __float2bfloat16(f);
  return *reinterpret_cast<unsigned short*>(&b);
}

// ---------------- prep1: X->bf16 convert + all 4 weight transpose-converts ------
__global__ __launch_bounds__(256) void k_prep1(
    const float* __restrict__ X, const float* __restrict__ Wq, const float* __restrict__ Wk,
    const float* __restrict__ Wv, const float* __restrict__ Wo,
    __hip_bfloat16* __restrict__ Xb, __hip_bfloat16* __restrict__ WqT,
    __hip_bfloat16* __restrict__ WkT, __hip_bfloat16* __restrict__ WvT,
    __hip_bfloat16* __restrict__ WoT) {
  __shared__ float tile[32][33];
  int b = blockIdx.x;
  if (b < 4096) {  // convert X
    int i = b * 256 + threadIdx.y * 32 + threadIdx.x;
    float4 v = ((const float4*)X)[i];
    ushort4 o;
    o.x = f2bu(v.x); o.y = f2bu(v.y); o.z = f2bu(v.z); o.w = f2bu(v.w);
    ((ushort4*)Xb)[i] = o;
    return;
  }
  b -= 4096;
  const float* src; __hip_bfloat16* dst; int xtiles;
  if (b < 4096)      { src = Wq; dst = WqT; xtiles = 64; }
  else if (b < 8192) { src = Wo; dst = WoT; xtiles = 64; b -= 4096; }
  else if (b < 9216) { src = Wk; dst = WkT; xtiles = 16; b -= 8192; }
  else               { src = Wv; dst = WvT; xtiles = 16; b -= 9216; }
  const int C = xtiles * 32;
  int bx = (b % xtiles) * 32;
  int by = (b / xtiles) * 32;
  int tx = threadIdx.x, ty = threadIdx.y;
#pragma unroll
  for (int i = 0; i < 4; i++)
    tile[ty + i * 8][tx] = src[(size_t)(by + ty + i * 8) * C + bx + tx];
  __syncthreads();
#pragma unroll
  for (int i = 0; i < 4; i++)
    dst[(size_t)(bx + ty + i * 8) * HH + by + tx] = __float2bfloat16(tile[tx][ty + i * 8]);
}

// ---------------- QKV GEMM + RoPE/V-transpose epilogue (r8, verified) ----------
// 64Mx128N tile, BK=64 dbuf, 48KB LDS, grid 768 = 3/CU. Q gets RoPE*scale,
// K gets RoPE, V written transposed into Vt[HKV][S].
__global__ __launch_bounds__(256, 3) void k_gemm_qkv(
    const __hip_bfloat16* __restrict__ A, const __hip_bfloat16* __restrict__ B,
    __hip_bfloat16* __restrict__ Qb, __hip_bfloat16* __restrict__ Kb,
    __hip_bfloat16* __restrict__ Vt, const int* __restrict__ pos) {
  __shared__ __align__(16) __hip_bfloat16 sA0[64 * 64];
  __shared__ __align__(16) __hip_bfloat16 sB0[128 * 64];
  __shared__ __align__(16) __hip_bfloat16 sA1[64 * 64];
  __shared__ __align__(16) __hip_bfloat16 sB1[128 * 64];
  const int tid = threadIdx.x;
  const int lane = tid & 63;
  const int wave = tid >> 6;
  const int bm = blockIdx.y * 64;
  const int bn = blockIdx.x * 128;
  const int wm = (wave & 1) * 32;
  const int wn = (wave >> 1) * 64;
  const int am = lane & 15;
  const int ch = lane >> 4;

  f32x4 acc[2][4] = {};

  auto stage = [&](__hip_bfloat16* sA, __hip_bfloat16* sB, int k0) {
#pragma unroll
    for (int q = 0; q < 2; q++) {
      int c = q * 256 + tid;
      int row = c >> 3, kp = c & 7;
      int col = (kp ^ (row & 7)) * 8;
      async_ld16(A + (size_t)(bm + row) * HH + k0 + col, (char*)sA + c * 16);
    }
#pragma unroll
    for (int q = 0; q < 4; q++) {
      int c = q * 256 + tid;
      int row = c >> 3, kp = c & 7;
      int col = (kp ^ (row & 7)) * 8;
      async_ld16(B + (size_t)(bn + row) * HH + k0 + col, (char*)sB + c * 16);
    }
  };
  auto compute = [&](const __hip_bfloat16* sA, const __hip_bfloat16* sB) {
#pragma unroll
    for (int kb = 0; kb < 2; kb++) {
      bf16x8 a[2], b[4];
#pragma unroll
      for (int i = 0; i < 2; i++) {
        int row = wm + i * 16 + am;
        a[i] = *(const bf16x8*)(sA + row * 64 + (((kb * 4 + ch) ^ (row & 7)) * 8));
      }
#pragma unroll
      for (int j = 0; j < 4; j++) {
        int row = wn + j * 16 + am;
        b[j] = *(const bf16x8*)(sB + row * 64 + (((kb * 4 + ch) ^ (row & 7)) * 8));
      }
#pragma unroll
      for (int i = 0; i < 2; i++)
#pragma unroll
        for (int j = 0; j < 4; j++)
          acc[i][j] = __builtin_amdgcn_mfma_f32_16x16x32_bf16(a[i], b[j], acc[i][j], 0, 0, 0);
    }
  };

  stage(sA0, sB0, 0);
  int k0 = 0;
  while (true) {
    __syncthreads();
    if (k0 + 64 < HH) stage(sA1, sB1, k0 + 64);
    compute(sA0, sB0);
    k0 += 64; if (k0 >= HH) break;
    __syncthreads();
    if (k0 + 64 < HH) stage(sA0, sB0, k0 + 64);
    compute(sA1, sB1);
    k0 += 64; if (k0 >= HH) break;
  }

  const bool isV = (bn >= HH + HKV);     // block-uniform (2560 is 128-aligned)
  if (isV) {
#pragma unroll
    for (int j = 0; j < 4; j++) {
      int lc = bn + wn + j * 16 + am - (HH + HKV);
#pragma unroll
      for (int i = 0; i < 2; i++) {
        int row = bm + wm + i * 16 + ch * 4;
        ushort4 o;
        o.x = f2bu(acc[i][j][0]); o.y = f2bu(acc[i][j][1]);
        o.z = f2bu(acc[i][j][2]); o.w = f2bu(acc[i][j][3]);
        *(ushort4*)(Vt + (size_t)lc * SS + row) = o;
      }
    }
  } else {
    const float SCLQ = 0.08838834764831845f * 1.4426950408889634f; // 1/sqrt(128)*log2e
    const float L2T_D64 = 0.20762050593046837f;                    // log2(10000)/64
    const bool isQ = (bn < HH);
    float posr[2][4];
#pragma unroll
    for (int i = 0; i < 2; i++)
#pragma unroll
      for (int r = 0; r < 4; r++)
        posr[i][r] = (float)pos[bm + wm + i * 16 + ch * 4 + r];
    const float sgn = (am & 1) ? 1.0f : -1.0f;
#pragma unroll
    for (int j = 0; j < 4; j++) {
      int col = bn + wn + j * 16 + am;
      int lc = isQ ? col : (col - HH);
      float freq = exp2f(-L2T_D64 * (float)((lc >> 1) & 63));
#pragma unroll
      for (int i = 0; i < 2; i++)
#pragma unroll
        for (int r = 0; r < 4; r++) {
          float v = acc[i][j][r];
          float px = __shfl_xor(v, 1, 64);
          float ang = posr[i][r] * freq;
          float sn, cs;
          sincosf(ang, &sn, &cs);
          float o = v * cs + sgn * px * sn;
          int row = bm + wm + i * 16 + ch * 4 + r;
          if (isQ) Qb[(size_t)row * HH + col] = __float2bfloat16(o * SCLQ);
          else     Kb[(size_t)row * HKV + lc] = __float2bfloat16(o);
        }
    }
  }
}

// ---------------- out-proj GEMM: 64x128 tile, BK=64 dbuf (round-6 verified) -----
__global__ __launch_bounds__(256, 3) void k_gemm_out(
    const __hip_bfloat16* __restrict__ A, const __hip_bfloat16* __restrict__ B,
    float* __restrict__ C) {
  __shared__ __align__(16) __hip_bfloat16 sA0[64 * 64];
  __shared__ __align__(16) __hip_bfloat16 sB0[128 * 64];
  __shared__ __align__(16) __hip_bfloat16 sA1[64 * 64];
  __shared__ __align__(16) __hip_bfloat16 sB1[128 * 64];
  const int tid = threadIdx.x;
  const int lane = tid & 63;
  const int wave = tid >> 6;
  const int bm = blockIdx.y * 64;
  const int bn = blockIdx.x * 128;
  const int wm = (wave & 1) * 32;
  const int wn = (wave >> 1) * 64;
  const int am = lane & 15;
  const int ch = lane >> 4;

  f32x4 acc[2][4] = {};

  auto stage = [&](__hip_bfloat16* sA, __hip_bfloat16* sB, int k0) {
#pragma unroll
    for (int q = 0; q < 2; q++) {
      int c = q * 256 + tid;
      int row = c >> 3, kp = c & 7;
      int col = (kp ^ (row & 7)) * 8;
      async_ld16(A + (size_t)(bm + row) * HH + k0 + col, (char*)sA + c * 16);
    }
#pragma unroll
    for (int q = 0; q < 4; q++) {
      int c = q * 256 + tid;
      int row = c >> 3, kp = c & 7;
      int col = (kp ^ (row & 7)) * 8;
      async_ld16(B + (size_t)(bn + row) * HH + k0 + col, (char*)sB + c * 16);
    }
  };
  auto compute = [&](const __hip_bfloat16* sA, const __hip_bfloat16* sB) {
#pragma unroll
    for (int kb = 0; kb < 2; kb++) {
      bf16x8 a[2], b[4];
#pragma unroll
      for (int i = 0; i < 2; i++) {
        int row = wm + i * 16 + am;
        a[i] = *(const bf16x8*)(sA + row * 64 + (((kb * 4 + ch) ^ (row & 7)) * 8));
      }
#pragma unroll
      for (int j = 0; j < 4; j++) {
        int row = wn + j * 16 + am;
        b[j] = *(const bf16x8*)(sB + row * 64 + (((kb * 4 + ch) ^ (row & 7)) * 8));
      }
#pragma unroll
      for (int i = 0; i < 2; i++)
#pragma unroll
        for (int j = 0; j < 4; j++)
          acc[i][j] = __builtin_amdgcn_mfma_f32_16x16x32_bf16(a[i], b[j], acc[i][j], 0, 0, 0);
    }
  };

  stage(sA0, sB0, 0);
  int k0 = 0;
  while (true) {
    __syncthreads();
    if (k0 + 64 < HH) stage(sA1, sB1, k0 + 64);
    compute(sA0, sB0);
    k0 += 64; if (k0 >= HH) break;
    __syncthreads();
    if (k0 + 64 < HH) stage(sA0, sB0, k0 + 64);
    compute(sA1, sB1);
    k0 += 64; if (k0 >= HH) break;
  }

#pragma unroll
  for (int i = 0; i < 2; i++)
#pragma unroll
    for (int j = 0; j < 4; j++)
#pragma unroll
      for (int r = 0; r < 4; r++) {
        int row = bm + wm + i * 16 + ch * 4 + r;
        int col = bn + wn + j * 16 + am;
        C[(size_t)row * HH + col] = acc[i][j][r];
      }
}

// ---------------- flash attention, kv-range split ----------------
// 1024 blocks: (head, 64-row q-tile, kv-half). Each (h,qt) splits its kv tiles
// [0..qt] into two halves -> avg 8.25 tiles/block, big blocks dispatched first
// (qt descending) so the scheduler backfills -> steadier 8 waves/CU vs the old
// pairing whose short block drained early (Occupancy 11.5%).
// Fixed-max softmax (max=8 log2-units) makes the cross-block merge commutative:
// partial O and l are ADDED into fp32 Obuf/Lbuf via HW atomics (exactly 2
// contributors per element -> deterministic). Normalization in k_norm.
__global__ __launch_bounds__(256, 2) void k_attn(
    const __hip_bfloat16* __restrict__ Qb,   // [S][H], pre-scaled by 1/sqrt(d)*log2e
    const __hip_bfloat16* __restrict__ Kb,   // [S][HKV]
    const __hip_bfloat16* __restrict__ Vt,   // [HKV][S]
    const int* __restrict__ amv, const int* __restrict__ seg,
    float* __restrict__ Obuf,                // [S][H] fp32, zeroed
    float* __restrict__ Lbuf) {              // [S][NH] fp32, zeroed
  __shared__ __align__(16) __hip_bfloat16 sK[2][64 * 128];  // 2x16KB, [key][d]
  __shared__ __align__(16) __hip_bfloat16 sV[2][128 * 64];  // 2x16KB, [d][key]
  __shared__ __align__(16) __hip_bfloat16 sPall[4][16 * 64]; // 8KB, per-wave
  __shared__ int sInfo[2][64];

  const int bid = blockIdx.x;
  const int qt = 31 - (bid >> 5);          // big q-tiles first
  const int h = (bid >> 1) & 15;
  const int half = bid & 1;
  const int T = qt + 1;                    // total 64-key tiles for this q-tile
  const int n0 = (T + 1) >> 1;
  const int kt0 = half ? n0 : 0;
  const int kt1 = half ? T : n0;
  if (kt0 >= kt1) return;                  // empty half (qt=0)

  const int kvh = h >> 2;
  const int tid = threadIdx.x, lane = tid & 63, w = tid >> 6;
  const int am = lane & 15, ch = lane >> 4;
  const int qrow0 = qt * 64 + w * 16;
  char* sP = (char*)&sPall[w][0];

  bf16x8 qf[4];
#pragma unroll
  for (int ks = 0; ks < 4; ks++)
    qf[ks] = *(const bf16x8*)(Qb + (size_t)(qrow0 + am) * HH + h * HD + ks * 32 + ch * 8);

  int segq[4];
#pragma unroll
  for (int r = 0; r < 4; r++) segq[r] = seg[qrow0 + ch * 4 + r];

  f32x4 o_acc[8] = {};
  float l_s[4] = {0.f, 0.f, 0.f, 0.f};

  auto stage = [&](int kt, int p) {
#pragma unroll
    for (int q = 0; q < 4; q++) {        // K tile: 1024 chunks, [key][16 chunks]
      int c = q * 256 + tid;
      int row = c >> 4, kp = c & 15;
      int col = (kp ^ (row & 15)) * 8;
      async_ld16(Kb + (size_t)(kt * 64 + row) * HKV + kvh * 128 + col, (char*)sK[p] + c * 16);
    }
#pragma unroll
    for (int q = 0; q < 4; q++) {        // V tile: 1024 chunks, [d][8 chunks]
      int c = q * 256 + tid;
      int row = c >> 3, kp = c & 7;
      int col = (kp ^ (row & 7)) * 8;
      async_ld16(Vt + (size_t)(kvh * 128 + row) * SS + kt * 64 + col, (char*)sV[p] + c * 16);
    }
    if (tid < 64) {
      int kidx = kt * 64 + tid;
      sInfo[p][tid] = (amv[kidx] > 0) ? seg[kidx] : 0x7fffffff;
    }
  };

  stage(kt0, 0);
  for (int kt = kt0; kt < kt1; kt++) {
    const int p = (kt - kt0) & 1;
    __syncthreads();
    if (kt + 1 < kt1) stage(kt + 1, p ^ 1);

    // S = Q K^T  (M=16 q, N=64 keys, K=128)
    f32x4 sacc[4] = {};
#pragma unroll
    for (int ks = 0; ks < 4; ks++)
#pragma unroll
      for (int jt = 0; jt < 4; jt++) {
        bf16x8 kf = *(const bf16x8*)(sK[p] + (jt * 16 + am) * 128 + (((ks * 4 + ch) ^ am) * 8));
        sacc[jt] = __builtin_amdgcn_mfma_f32_16x16x32_bf16(qf[ks], kf, sacc[jt], 0, 0, 0);
      }

#pragma unroll
    for (int jt = 0; jt < 4; jt++) {
      int kloc = jt * 16 + am;
      int kinfo = sInfo[p][kloc];
#pragma unroll
      for (int r = 0; r < 4; r++) {
        int qrow = qrow0 + ch * 4 + r;
        bool ok = (kinfo == segq[r]) && (kt * 64 + kloc <= qrow);
        float pv = ok ? exp2f(sacc[jt][r] - 8.0f) : 0.0f;
        l_s[r] += pv;
        int row = ch * 4 + r;
        int chunk = (jt * 2 + (am >> 3)) ^ (row & 7);
        *(__hip_bfloat16*)(sP + row * 128 + chunk * 16 + (am & 7) * 2) =
            __float2bfloat16(pv);
      }
    }

    // O += P V  (M=16 q, N=128 d, K=64 keys)
#pragma unroll
    for (int ks = 0; ks < 2; ks++) {
      bf16x8 pf = *(const bf16x8*)(sP + am * 128 + (((ks * 4 + ch) ^ (am & 7)) * 16));
#pragma unroll
      for (int jt = 0; jt < 8; jt++) {
        int vrow = jt * 16 + am;
        bf16x8 vf = *(const bf16x8*)(sV[p] + vrow * 64 + (((ks * 4 + ch) ^ (vrow & 7)) * 8));
        o_acc[jt] = __builtin_amdgcn_mfma_f32_16x16x32_bf16(pf, vf, o_acc[jt], 0, 0, 0);
      }
    }
  }

  // partial epilogue: reduce l over the 16 lanes sharing each row, atomically merge
#pragma unroll
  for (int off = 1; off < 16; off <<= 1)
#pragma unroll
    for (int r = 0; r < 4; r++) l_s[r] += __shfl_xor(l_s[r], off, 64);
  if (am == 0)
#pragma unroll
    for (int r = 0; r < 4; r++)
      unsafeAtomicAdd(Lbuf + (size_t)(qrow0 + ch * 4 + r) * NH + h, l_s[r]);
#pragma unroll
  for (int jt = 0; jt < 8; jt++)
#pragma unroll
    for (int r = 0; r < 4; r++) {
      int row = qrow0 + ch * 4 + r;
      unsafeAtomicAdd(Obuf + (size_t)row * HH + h * HD + jt * 16 + am, o_acc[jt][r]);
    }
}

// ---------------- normalize + convert: Ab = bf16(Obuf / Lbuf) ----------------
__global__ __launch_bounds__(256) void k_norm(
    const float* __restrict__ Obuf, const float* __restrict__ Lbuf,
    __hip_bfloat16* __restrict__ Ab) {
  int i = blockIdx.x * 256 + threadIdx.x;  // float4 index; 512 per row
  int s = i >> 9;
  int hIdx = (i & 511) >> 5;               // 32 float4 per head
  float inv = 1.0f / Lbuf[(size_t)s * NH + hIdx];
  float4 v = ((const float4*)Obuf)[i];
  ushort4 o;
  o.x = f2bu(v.x * inv); o.y = f2bu(v.y * inv);
  o.z = f2bu(v.z * inv); o.w = f2bu(v.w * inv);
  ((ushort4*)Ab)[i] = o;
}

extern "C" void kernel_launch(void* const* d_in, const int* in_sizes, int n_in,
                              void* d_out, int out_size, void* d_ws, size_t ws_size,
                              hipStream_t stream) {
  const float* X  = (const float*)d_in[0];
  const int* amv  = (const int*)d_in[1];
  const int* seg  = (const int*)d_in[2];
  const int* pos  = (const int*)d_in[3];
  const float* Wq = (const float*)d_in[4];
  const float* Wk = (const float*)d_in[5];
  const float* Wv = (const float*)d_in[6];
  const float* Wo = (const float*)d_in[7];
  float* out = (float*)d_out;

  // workspace carve-up (~62 MB); WqT/WkT/WvT contiguous; Obuf+Lbuf adjacent for
  // a single memset.
  char* ws = (char*)d_ws;
  size_t off = 0;
  auto alloc = [&](size_t bytes) { void* p = ws + off; off += (bytes + 255) & ~(size_t)255; return p; };
  __hip_bfloat16* Xb   = (__hip_bfloat16*)alloc((size_t)SS * HH * 2);
  __hip_bfloat16* WqT  = (__hip_bfloat16*)alloc((size_t)HH * HH * 2);
  __hip_bfloat16* WkT  = (__hip_bfloat16*)alloc((size_t)HKV * HH * 2);
  __hip_bfloat16* WvT  = (__hip_bfloat16*)alloc((size_t)HKV * HH * 2);
  __hip_bfloat16* WoT  = (__hip_bfloat16*)alloc((size_t)HH * HH * 2);
  __hip_bfloat16* Qb   = (__hip_bfloat16*)alloc((size_t)SS * HH * 2);
  __hip_bfloat16* Kb   = (__hip_bfloat16*)alloc((size_t)SS * HKV * 2);
  __hip_bfloat16* Vt   = (__hip_bfloat16*)alloc((size_t)HKV * SS * 2);
  __hip_bfloat16* Ab   = (__hip_bfloat16*)alloc((size_t)SS * HH * 2);
  float*          Obuf = (float*)alloc((size_t)SS * HH * 4);
  float*          Lbuf = (float*)alloc((size_t)SS * NH * 4);
  (void)WkT; (void)WvT;

  // 0) zero the attention accumulators (one contiguous memset)
  hipMemsetAsync(Obuf, 0, (size_t)SS * HH * 4 + ((size_t)SS * NH * 4 + 255 & ~(size_t)255), stream);
  // 1) convert X + transpose-convert all weights (one launch)
  k_prep1<<<dim3(14336), dim3(32, 8), 0, stream>>>(X, Wq, Wk, Wv, Wo, Xb, WqT, WkT, WvT, WoT);
  // 2) fused QKV projection: RoPE'd Qb (scaled) / Kb, V written transposed to Vt
  k_gemm_qkv<<<dim3(NQKV / 128, SS / 64), 256, 0, stream>>>(Xb, WqT, Qb, Kb, Vt, pos);
  // 3) attention: 1024 kv-split blocks, big-first; partials merged via fp32 atomics
  k_attn<<<dim3(1024), 256, 0, stream>>>(Qb, Kb, Vt, amv, seg, Obuf, Lbuf);
  // 4) normalize + bf16 convert
  k_norm<<<dim3(SS * HH / 4 / 256), 256, 0, stream>>>(Obuf, Lbuf, Ab);
  // 5) output projection (round-6 verified config)
  k_gemm_out<<<dim3(HH / 128, SS / 64), 256, 0, stream>>>(Ab, WoT, out);
}